// Round 6
// baseline (432.804 us; speedup 1.0000x reference)
//
#include <hip/hip_runtime.h>
#include <stdint.h>

// ---------------------------------------------------------------------------
// QuantLinear:  Y[n,m] = cs[n]*rs[m]*( Sint[n,m] - zp[n]*Wsum[m] ) + b[m]
// R8 = R7 resubmitted unchanged after a broker-level container failure
// (same precedent as R2's note; kernel re-audited: uniform barriers, vmcnt
// accounting and buffer-rotation races re-verified on paper).
//
// R7: occupancy-tier rewrite of the GEMM.
//   Diagnosis (R3-R6): three schedules all 40-44% MfmaUtil because
//   92 VGPR + 128 AGPR = 220 regs -> 2 waves/SIMD (64-granule alloc) and
//   128 KB LDS -> 1 block/CU; per-wave MFMA duty 21% x 2 waves = 42% cap.
//   Fix: 128x128 tile, 256 thr (4 waves, 2x2), 64x64/wave -> acc 64 AGPR,
//   __launch_bounds__(256,4) caps VGPR<=64 -> 4 waves/SIMD tier; BK=64 with
//   THREE 16KB LDS buffers (48 KB) -> 3 blocks/CU, 3 independent waves/SIMD.
//   Schedule: minimal m97-style, ONE s_barrier per K-tile, counted vmcnt(4)
//   (never 0), 2-tile staging lead into the just-freed buffer, compiler
//   counted-lgkm pipelines slice1 reads under slice0 MFMAs. No setprio
//   (T5 ~0/neg in compiler-scheduled structures, m190).
//   LDS swizzle unchanged (64B rows, phys chunk = c ^ ((row>>2)&3), both
//   sides; SQ_LDS_BANK_CONFLICT == 0 verified in R5/R6).
//   XCD slab swizzle: each XCD owns a 4-m-col stripe -> its Wq working set
//   (2 MB) stays L2-resident; Xq panels reused 4x back-to-back, L3-backed.
// Quant kernel unchanged (if quant > new gemm it surfaces in top-5 ->
// finally measures the ~250 us non-gemm residue).
// ---------------------------------------------------------------------------

typedef __attribute__((ext_vector_type(4)))  int int4v;
typedef __attribute__((ext_vector_type(16))) int int16v;

__device__ __forceinline__ void async_load16(const void* g, void* l) {
    __builtin_amdgcn_global_load_lds(
        (const __attribute__((address_space(1))) void*)g,
        (__attribute__((address_space(3))) void*)l, 16, 0, 0);
}

__device__ __forceinline__ int quant_clip(float v) {
    // matches np: clip(rint(v), -128, 127); rintf = round-half-even
    return (int)fminf(fmaxf(rintf(v), -128.f), 127.f);
}

// ---------------------------------------------------------------------------
// Merged quant kernel (unchanged). Blocks [0,M) quantize W rows; blocks
// [M,M+N) quantize X token-rows. 256 threads, 4 x float4 per thread.
// ---------------------------------------------------------------------------
__global__ __launch_bounds__(256) void quant_kernel(
    const float* __restrict__ W, const float* __restrict__ X,
    int8_t* __restrict__ Wq, int8_t* __restrict__ Xq,
    float* __restrict__ row_scale, int* __restrict__ wsum,
    float* __restrict__ col_scale, int* __restrict__ zp, int M, int K) {
    const int blk  = blockIdx.x;
    const int tid  = threadIdx.x;
    const int lane = tid & 63;
    const int wv   = tid >> 6;
    __shared__ float sred0[4], sred1[4];
    __shared__ int   isum[4];

    if (blk < M) {
        const int row = blk;
        const float4* w4 = (const float4*)(W + (size_t)row * K);
        float4 vals[4];
        float amax = 0.f;
#pragma unroll
        for (int i = 0; i < 4; ++i) {
            float4 v = w4[tid + i * 256];
            vals[i] = v;
            amax = fmaxf(amax, fmaxf(fmaxf(fabsf(v.x), fabsf(v.y)),
                                     fmaxf(fabsf(v.z), fabsf(v.w))));
        }
#pragma unroll
        for (int off = 32; off > 0; off >>= 1)
            amax = fmaxf(amax, __shfl_down(amax, off, 64));
        if (lane == 0) sred0[wv] = amax;
        __syncthreads();
        amax = fmaxf(fmaxf(sred0[0], sred0[1]), fmaxf(sred0[2], sred0[3]));

        const float scale = (amax > 0.f) ? (amax / 127.f) : 1.f;
        const float inv   = 1.f / scale;

        int ssum = 0;
        int* wq32 = (int*)(Wq + (size_t)row * K);
#pragma unroll
        for (int i = 0; i < 4; ++i) {
            float4 v = vals[i];
            int q0 = quant_clip(v.x * inv);
            int q1 = quant_clip(v.y * inv);
            int q2 = quant_clip(v.z * inv);
            int q3 = quant_clip(v.w * inv);
            ssum += q0 + q1 + q2 + q3;
            wq32[tid + i * 256] =
                (q0 & 0xff) | ((q1 & 0xff) << 8) | ((q2 & 0xff) << 16) | ((q3 & 0xff) << 24);
        }
#pragma unroll
        for (int off = 32; off > 0; off >>= 1)
            ssum += __shfl_down(ssum, off, 64);
        if (lane == 0) isum[wv] = ssum;
        __syncthreads();
        if (tid == 0) {
            wsum[row] = isum[0] + isum[1] + isum[2] + isum[3];
            row_scale[row] = scale;
        }
    } else {
        const int row = blk - M;
        const float4* x4 = (const float4*)(X + (size_t)row * K);
        float4 vals[4];
        float vmin = 3.402823466e+38f, vmax = -3.402823466e+38f;
#pragma unroll
        for (int i = 0; i < 4; ++i) {
            float4 v = x4[tid + i * 256];
            vals[i] = v;
            vmin = fminf(vmin, fminf(fminf(v.x, v.y), fminf(v.z, v.w)));
            vmax = fmaxf(vmax, fmaxf(fmaxf(v.x, v.y), fmaxf(v.z, v.w)));
        }
#pragma unroll
        for (int off = 32; off > 0; off >>= 1) {
            vmin = fminf(vmin, __shfl_down(vmin, off, 64));
            vmax = fmaxf(vmax, __shfl_down(vmax, off, 64));
        }
        if (lane == 0) { sred0[wv] = vmin; sred1[wv] = vmax; }
        __syncthreads();
        vmin = fminf(fminf(sred0[0], sred0[1]), fminf(sred0[2], sred0[3]));
        vmax = fmaxf(fmaxf(sred1[0], sred1[1]), fmaxf(sred1[2], sred1[3]));

        const float rng   = vmax - vmin;
        const float scale = (rng > 0.f) ? (rng / 255.f) : 1.f;
        const float inv   = 1.f / scale;
        const float zpf   = fminf(fmaxf(rintf(-128.f - vmin * inv), -128.f), 127.f);

        int* xq32 = (int*)(Xq + (size_t)row * K);
#pragma unroll
        for (int i = 0; i < 4; ++i) {
            float4 v = vals[i];
            int q0 = quant_clip(v.x * inv + zpf);
            int q1 = quant_clip(v.y * inv + zpf);
            int q2 = quant_clip(v.z * inv + zpf);
            int q3 = quant_clip(v.w * inv + zpf);
            xq32[tid + i * 256] =
                (q0 & 0xff) | ((q1 & 0xff) << 8) | ((q2 & 0xff) << 16) | ((q3 & 0xff) << 24);
        }
        if (tid == 0) {
            col_scale[row] = scale;
            zp[row] = (int)zpf;
        }
    }
}

// ---------------------------------------------------------------------------
// int8 GEMM, 128x128 tile, 4 waves (2x2, 64x64/wave), BK=64, 3-buffer LDS.
//
// LDS buffer (16 KB): A = 128 rows x 64B (+0), B = 128 rows x 64B (+8192).
// Row r, logical 16B chunk c stored at physical chunk c ^ ((r>>2)&3); XOR
// folded into the per-lane GLOBAL source (DMA dest is linear) and applied
// again at ds_read. Verified conflict-free (R5/R6: SQ_LDS_BANK_CONFLICT=0).
//
// Per K-tile t: buffers rotate (pR = data(t), pN = data(t+1), pS = free).
//   issue 4 DMA: tile t+2 -> pS   (A rows 0-63, 64-127; B same)
//   8 x ds_read_b128 (slice0 cc0, slice1 cc1) from pR
//   8 x mfma (compiler pipelines slice1 reads under slice0 MFMAs via
//     counted lgkmcnt)
//   s_waitcnt vmcnt(4)   -- retires tile t+1's 4 DMAs; t+2's 4 stay in flight
//   sched_barrier(0); s_barrier   -- publishes t+1 residency to all waves
//   rotate (pR,pN,pS) <- (pN,pS,pR)
// Overwrite safety: pS held t-1's data; every wave consumed its t-1 reads
// (lgkm before MFMA) before arriving at t-1's end barrier, and the t+2 DMAs
// are issued after that barrier. Tail: ko2 clamps to NT-1 (re-stages
// identical bytes into the unused third buffer; race-free).
// ---------------------------------------------------------------------------
__global__ __launch_bounds__(256, 4) void gemm_i8_kernel(
    const int8_t* __restrict__ Xq, const int8_t* __restrict__ Wq,
    const float* __restrict__ cs, const int* __restrict__ zp,
    const float* __restrict__ rs, const int* __restrict__ wsum,
    const float* __restrict__ bias, float* __restrict__ out,
    int N, int M, int K) {
    __shared__ __align__(16) int8_t lds[49152];  // 3 x 16 KB

    const int t    = threadIdx.x;
    const int wv   = t >> 6;       // 0..3
    const int lane = t & 63;
    const int r32  = lane & 31;
    const int half = lane >> 5;
    const int wn   = wv >> 1;      // 0..1  (n-wave)
    const int wm   = wv & 1;       // 0..1  (m-wave)

    // ---- XCD slab swizzle: XCD x owns m-cols [x*mpx, (x+1)*mpx) ----
    const int mcols = M >> 7;            // 32
    const int mpx   = mcols >> 3;        // 4 m-cols per XCD
    const int lin   = blockIdx.x;
    const int xcd   = lin & 7;
    const int p     = lin >> 3;          // 0..255 within XCD
    const int m0    = (xcd * mpx + (p & (mpx - 1))) << 7;
    const int n0    = (p / mpx) << 7;

    const int NT = K >> 6;  // K-tiles of 64

    // ---- staging map: one async_load16 line = 4 KB (64 rows x 64B);
    // lane l -> row wv*16 + l/4, phys chunk l&3; global source supplies
    // logical chunk (l&3) ^ ((row>>2)&3) = (l&3) ^ ((l>>4)&3).
    const int lrow   = (wv << 4) + (lane >> 2);               // 0..63
    const int srcOff = (((lane & 3) ^ ((lane >> 4) & 3)) << 4);
    const int8_t* gA = Xq + (size_t)(n0 + lrow) * K + srcOff;
    const int8_t* gB = Wq + (size_t)(m0 + lrow) * K + srcOff;
    const size_t rowK64 = (size_t)K << 6;   // +64 rows
    const int wvOff = wv << 10;

    // ---- reader offsets: rows of the 128x64B region, swizzle on chunk ----
    const int aoff0 = ((wn << 6) + r32) << 6;
    const int aoff1 = ((wn << 6) + 32 + r32) << 6;
    const int boff0 = (((wm << 6) + r32) << 6) + 8192;
    const int boff1 = (((wm << 6) + 32 + r32) << 6) + 8192;
    const int sw4 = (r32 >> 2) & 3;             // row bases are 0 mod 32
    const int cc0 = ((half ^ sw4) << 4);        // k-slice 0
    const int cc1 = (((2 + half) ^ sw4) << 4);  // k-slice 1

    int16v acc00 = (int16v)(0), acc01 = (int16v)(0);
    int16v acc10 = (int16v)(0), acc11 = (int16v)(0);

    int8_t* b0 = lds;
    int8_t* b1 = lds + 16384;
    int8_t* b2 = lds + 32768;

    // ---- prologue: stage tile0 -> b0, tile1 -> b1 (8 DMAs/wave) ----
    async_load16(gA,               b0 + wvOff);
    async_load16(gA + rowK64,      b0 + 4096 + wvOff);
    async_load16(gB,               b0 + 8192 + wvOff);
    async_load16(gB + rowK64,      b0 + 12288 + wvOff);
    async_load16(gA + 64,          b1 + wvOff);
    async_load16(gA + 64 + rowK64, b1 + 4096 + wvOff);
    async_load16(gB + 64,          b1 + 8192 + wvOff);
    async_load16(gB + 64 + rowK64, b1 + 12288 + wvOff);
    asm volatile("s_waitcnt vmcnt(4)" ::: "memory");  // tile0 resident
    __builtin_amdgcn_sched_barrier(0);
    __builtin_amdgcn_s_barrier();

    int8_t* pR = b0;
    int8_t* pN = b1;
    int8_t* pS = b2;

    for (int tt = 0; tt < NT; ++tt) {
        const int ko2 = ((tt + 2 < NT) ? tt + 2 : NT - 1) << 6;

        // stage tile t+2 into the just-freed buffer
        async_load16(gA + ko2,          pS + wvOff);
        async_load16(gA + ko2 + rowK64, pS + 4096 + wvOff);
        async_load16(gB + ko2,          pS + 8192 + wvOff);
        async_load16(gB + ko2 + rowK64, pS + 12288 + wvOff);

        // slice 0
        int4v a0 = *(const int4v*)(pR + aoff0 + cc0);
        int4v b0v = *(const int4v*)(pR + boff0 + cc0);
        int4v b1v = *(const int4v*)(pR + boff1 + cc0);
        int4v a1 = *(const int4v*)(pR + aoff1 + cc0);
        // slice 1
        int4v a2 = *(const int4v*)(pR + aoff0 + cc1);
        int4v b2v = *(const int4v*)(pR + boff0 + cc1);
        int4v b3v = *(const int4v*)(pR + boff1 + cc1);
        int4v a3 = *(const int4v*)(pR + aoff1 + cc1);

        acc00 = __builtin_amdgcn_mfma_i32_32x32x32_i8(a0, b0v, acc00, 0, 0, 0);
        acc01 = __builtin_amdgcn_mfma_i32_32x32x32_i8(a0, b1v, acc01, 0, 0, 0);
        acc10 = __builtin_amdgcn_mfma_i32_32x32x32_i8(a1, b0v, acc10, 0, 0, 0);
        acc11 = __builtin_amdgcn_mfma_i32_32x32x32_i8(a1, b1v, acc11, 0, 0, 0);
        acc00 = __builtin_amdgcn_mfma_i32_32x32x32_i8(a2, b2v, acc00, 0, 0, 0);
        acc01 = __builtin_amdgcn_mfma_i32_32x32x32_i8(a2, b3v, acc01, 0, 0, 0);
        acc10 = __builtin_amdgcn_mfma_i32_32x32x32_i8(a3, b2v, acc10, 0, 0, 0);
        acc11 = __builtin_amdgcn_mfma_i32_32x32x32_i8(a3, b3v, acc11, 0, 0, 0);

        // retire tile t+1's 4 DMAs (t+2's 4 remain in flight); publish
        asm volatile("s_waitcnt vmcnt(4)" ::: "memory");
        __builtin_amdgcn_sched_barrier(0);
        __builtin_amdgcn_s_barrier();

        int8_t* tmp = pR; pR = pN; pN = pS; pS = tmp;
    }

    // ---- epilogue: 32x32 C/D: col(m)=lane&31, row(n)=(reg&3)+8*(reg>>2)+4*half
    int   mm[2];
    float rsv[2], bv[2];
    int   wsv[2];
#pragma unroll
    for (int j = 0; j < 2; ++j) {
        mm[j]  = m0 + (wm << 6) + j * 32 + r32;
        rsv[j] = rs[mm[j]];
        bv[j]  = bias[mm[j]];
        wsv[j] = wsum[mm[j]];
    }
    const int16v* accp[2][2] = {{&acc00, &acc01}, {&acc10, &acc11}};
#pragma unroll
    for (int i = 0; i < 2; ++i) {
        const int nbase = n0 + (wn << 6) + i * 32 + (half << 2);
#pragma unroll
        for (int reg = 0; reg < 16; ++reg) {
            const int n = nbase + (reg & 3) + 8 * (reg >> 2);
            const float csn = cs[n];
            const int   zpn = zp[n];
#pragma unroll
            for (int j = 0; j < 2; ++j) {
                const int ival = (*accp[i][j])[reg] - zpn * wsv[j];
                out[(size_t)n * M + mm[j]] = csn * rsv[j] * (float)ival + bv[j];
            }
        }
    }
}

// ---------------------------------------------------------------------------
extern "C" void kernel_launch(void* const* d_in, const int* in_sizes, int n_in,
                              void* d_out, int out_size, void* d_ws, size_t ws_size,
                              hipStream_t stream) {
    const float* x = (const float*)d_in[0];
    const float* W = (const float*)d_in[1];
    const float* b = (const float*)d_in[2];
    float* out = (float*)d_out;

    const int M = in_sizes[2];            // 4096
    const int K = in_sizes[1] / M;        // 4096
    const int N = in_sizes[0] / K;        // 8192

    // workspace carve-up (~50.4 MB)
    int8_t* Xq = (int8_t*)d_ws;                       // N*K
    int8_t* Wq = Xq + (size_t)N * K;                  // M*K
    float* cs  = (float*)(Wq + (size_t)M * K);        // N
    int* zps   = (int*)(cs + N);                      // N
    float* rs  = (float*)(zps + M);                   // M  (sized N>=M; see carve)
    int* wsum  = (int*)(rs + M);                      // M

    // NOTE: carve identical to prior rounds: cs[N], zps[N], rs[M], wsum[M].
    // (rs pointer arithmetic uses zps + N below; restored exactly:)
    rs   = (float*)(zps + N);
    wsum = (int*)(rs + M);

    quant_kernel<<<dim3(M + N), dim3(256), 0, stream>>>(
        W, x, Wq, Xq, rs, wsum, cs, zps, M, K);
    gemm_i8_kernel<<<dim3((M >> 7) * (N >> 7)), dim3(256), 0, stream>>>(
        Xq, Wq, cs, zps, rs, wsum, b, out, N, M, K);
}